// Round 12
// baseline (95.278 us; speedup 1.0000x reference)
//
#include <hip/hip_runtime.h>

#define L2E 1.44269504088896340736f
#define LN2 0.69314718055994530942f
#define NEGB -1e30f

typedef float f32x4 __attribute__((ext_vector_type(4)));
typedef __bf16 bf16x8 __attribute__((ext_vector_type(8)));

// workspace layout (bytes)
static constexpr size_t WT_ALL_OFF   = 0;        // 80*768 bf16
static constexpr size_t WT_TYPE_OFF  = 122880;   // 512*768 bf16 (rows 500..511 zero)
static constexpr size_t EM_T_OFF     = 909312;   // 512*3*64 f32 (em_t[s][j][b])
static constexpr size_t SCORES_OFF   = 1302528;  // 64*512 f32
static constexpr size_t LABELS_T_OFF = 1433600;  // 512*64 i32
static constexpr size_t LEN_OFF      = 1564672;  // 64 i32
static constexpr size_t POOLED_OFF   = 2351360;  // 512*768 bf16
static constexpr size_t CNT_OFF      = 3399936;  // 1 u32 block counter
static constexpr size_t MATM_OFF     = 3400192;  // 64*9*64 f32
static constexpr size_t PSC_OFF      = 3547648;  // 64*64 f32
static constexpr size_t PQ_OFF       = 3564032;  // 512 rows * 8 octs * 4 f32 = 65536
static constexpr size_t VL_OFF       = 3629568;  // 512 f32

__device__ __forceinline__ unsigned short f2bf(float f) {
  unsigned u = __builtin_bit_cast(unsigned, f);
  u += 0x7FFFu + ((u >> 16) & 1u);
  return (unsigned short)(u >> 16);
}
__device__ __forceinline__ float sel3(float a, float b, float c, int i) {
  return i == 0 ? a : (i == 1 ? b : c);
}
__device__ __forceinline__ float lse3(float x, float y, float z) {
  float m = fmaxf(fmaxf(x, y), z);
  float p = exp2f((x - m) * L2E) + exp2f((y - m) * L2E) + exp2f((z - m) * L2E);
  return m + log2f(p) * LN2;
}
__device__ __forceinline__ bf16x8 pack8(float4 lo, float4 hi) {
  union { unsigned u[4]; bf16x8 v; } r;
  asm("v_cvt_pk_bf16_f32 %0, %1, %2" : "=v"(r.u[0]) : "v"(lo.x), "v"(lo.y));
  asm("v_cvt_pk_bf16_f32 %0, %1, %2" : "=v"(r.u[1]) : "v"(lo.z), "v"(lo.w));
  asm("v_cvt_pk_bf16_f32 %0, %1, %2" : "=v"(r.u[2]) : "v"(hi.x), "v"(hi.y));
  asm("v_cvt_pk_bf16_f32 %0, %1, %2" : "=v"(r.u[3]) : "v"(hi.z), "v"(hi.w));
  return r.v;
}
__device__ __forceinline__ void gload_lds16(const void* g, void* l) {
  __builtin_amdgcn_global_load_lds(
      (const __attribute__((address_space(1))) unsigned*)g,
      (__attribute__((address_space(3))) unsigned*)l, 16, 0, 0);
}

// ---------------- K_A: wt_all transpose + lengths + counter zero (14 blocks) -----------------
__global__ __launch_bounds__(256) void ka_prep(
    const float* __restrict__ W1, const float* __restrict__ Wpos,
    const int* __restrict__ amask, unsigned short* __restrict__ wt_all,
    int* __restrict__ lengths, unsigned* __restrict__ cnt) {
  const int bid = blockIdx.x, t = threadIdx.x;
  if (bid < 12) {                       // wt_all rows 0..63 = W1^T, 64x64 tiles over k
    __shared__ float tl[64][65];
    const int k0 = bid * 64;
    const int n = t & 63;
    #pragma unroll
    for (int i = 0; i < 16; ++i) {
      int k = i * 4 + (t >> 6);
      tl[k][n] = W1[(size_t)(k0 + k) * 64 + n];
    }
    __syncthreads();
    const int k = t & 63;
    #pragma unroll
    for (int i = 0; i < 16; ++i) {
      int nn = i * 4 + (t >> 6);
      wt_all[(size_t)nn * 768 + k0 + k] = f2bf(tl[k][nn]);
    }
  } else if (bid == 12) {               // wt_all rows 64..79 (Wpos cols + zero pad)
    for (int idx = t; idx < 16 * 768; idx += 256) {
      int n = 64 + idx / 768, k = idx % 768;
      float v = (n < 67) ? Wpos[k * 3 + (n - 64)] : 0.f;
      wt_all[(size_t)n * 768 + k] = f2bf(v);
    }
  } else {                              // lengths + counter zero
    __shared__ int part[256];
    int bb = t >> 2, qq = t & 3;
    const int4* mp = (const int4*)(amask + bb * 512 + qq * 128);
    int s = 0;
    #pragma unroll 8
    for (int i = 0; i < 32; ++i) { int4 v = mp[i]; s += v.x + v.y + v.z + v.w; }
    part[t] = s;
    __syncthreads();
    if (qq == 0) lengths[bb] = part[t] + part[t + 1] + part[t + 2] + part[t + 3];
    if (t == 0) *cnt = 0u;
  }
}

// ---------------- K1: [32768x768]@[768x80] bf16 MFMA, 4-buf 2-deep DMA pipeline --------------
__global__ __launch_bounds__(256) void k1_gemm(
    const float* __restrict__ hidden, const int* __restrict__ plab,
    const float* __restrict__ bpos, const float* __restrict__ b1,
    const float* __restrict__ W2, const float* __restrict__ b2,
    const float* __restrict__ biw, const unsigned short* __restrict__ wt_all,
    float* __restrict__ em_t, float* __restrict__ scores, int* __restrict__ labels_t) {
  __shared__ uint4 As[4][512];
  __shared__ uint4 Bs[4][512];
  const int t = threadIdx.x, w = t >> 6, l = t & 63;
  const int row0 = blockIdx.x * 64;
  const int c16 = l & 15, q = l >> 4;

  f32x4 acc[5];
  #pragma unroll
  for (int nt = 0; nt < 5; ++nt) acc[nt] = (f32x4){0.f, 0.f, 0.f, 0.f};

  auto stage = [&](int it) {
    const int bi = it & 3;
    const int k0 = it * 32;
    #pragma unroll
    for (int u = 0; u < 2; ++u) {
      int i = w * 128 + u * 64 + l;
      int row = i >> 3;
      int ss = (i & 7) ^ (row & 7);
      gload_lds16(hidden + (size_t)(row0 + row) * 768 + k0 + 4 * ss,
                  (void*)(As[bi] + (w * 128 + u * 64)));
    }
    #pragma unroll
    for (int u = 0; u < 2; ++u) {
      int i = w * 128 + u * 64 + l;
      int row = i >> 2;
      int ss = (i & 3) ^ ((row >> 1) & 3);
      gload_lds16(wt_all + (size_t)row * 768 + k0 + 8 * ss,
                  (void*)(Bs[bi] + (w * 128 + u * 64)));
    }
  };

  stage(0); stage(1);
  for (int it = 0; it < 24; ++it) {
    if (it < 22) stage(it + 2);
    if (it < 22)       asm volatile("s_waitcnt vmcnt(8)" ::: "memory");
    else if (it == 22) asm volatile("s_waitcnt vmcnt(4)" ::: "memory");
    else               asm volatile("s_waitcnt vmcnt(0)" ::: "memory");
    __builtin_amdgcn_s_barrier();
    __builtin_amdgcn_sched_barrier(0);

    const int bi = it & 3;
    const char* Ab = (const char*)As[bi];
    const char* Bb = (const char*)Bs[bi];
    const int arow = 16 * w + c16, r7 = arow & 7;
    float4 alo = *(const float4*)(Ab + arow * 128 + (((2 * q + 0) ^ r7) << 4));
    float4 ahi = *(const float4*)(Ab + arow * 128 + (((2 * q + 1) ^ r7) << 4));
    bf16x8 a = pack8(alo, ahi);
    #pragma unroll
    for (int nt = 0; nt < 5; ++nt) {
      const int brow = 16 * nt + c16;
      bf16x8 b = *(const bf16x8*)(Bb + brow * 64 + ((q ^ ((brow >> 1) & 3)) << 4));
      acc[nt] = __builtin_amdgcn_mfma_f32_16x16x32_bf16(a, b, acc[nt], 0, 0, 0);
    }
  }

  const float bias2 = b2[0];
  #pragma unroll
  for (int r = 0; r < 4; ++r) {
    float s = 0.f;
    #pragma unroll
    for (int nt = 0; nt < 4; ++nt) {
      int c = 16 * nt + c16;
      float x = acc[nt][r] + b1[c];
      float th = 1.f - 2.f / (1.f + exp2f(x * (2.f * L2E)));
      s += th * W2[c];
    }
    #pragma unroll
    for (int off = 1; off < 16; off <<= 1) s += __shfl_xor(s, off, 64);
    if (c16 == 0) {
      int row = row0 + 16 * w + 4 * q + r;
      scores[row] = s + bias2;
    }
  }
  if (c16 < 3) {
    const float bi = biw[0];
    #pragma unroll
    for (int r = 0; r < 4; ++r) {
      int row = row0 + 16 * w + 4 * q + r;
      int bb = row >> 9, ss = row & 511;
      int lab = plab[row];
      float wgt = (lab > 0) ? 1.f + bi : 1.f;
      float ev = (acc[4][r] + bpos[c16]) * wgt;
      em_t[(ss * 3 + c16) * 64 + bb] = ev;
      if (c16 == 0) labels_t[ss * 64 + bb] = lab;
    }
  }
}

// ---------------- KPC2: {pool 128 | k2a 16 | wt_type transpose 96} (240 x 256) ---------------
__global__ __launch_bounds__(256) void kpc2(
    const float* __restrict__ hidden, const float* __restrict__ scores,
    const int* __restrict__ tpos, unsigned short* __restrict__ pooled,
    const float* __restrict__ em_t, const int* __restrict__ labels_t,
    const int* __restrict__ lengths, const float* __restrict__ trans,
    const float* __restrict__ Wtype, unsigned short* __restrict__ wt_type,
    float* __restrict__ matM, float* __restrict__ psc) {
  const int bid = blockIdx.x, t = threadIdx.x, w = t >> 6, l = t & 63;

  if (bid < 128) {
    // pooling: wave w -> span bid*4 + w
    const int span = bid * 4 + w;
    const int b = span >> 3;
    const int st = tpos[span * 2], en = tpos[span * 2 + 1];
    int len = (st + en > 0) ? (en - st) : 0;
    float sv[7], aw[7];
    float wm = -1e30f;
    #pragma unroll
    for (int j = 0; j < 7; ++j) {
      sv[j] = (j < len) ? scores[b * 512 + st + j] : -1e30f;
      wm = fmaxf(wm, sv[j]);
    }
    float den = 0.f;
    #pragma unroll
    for (int j = 0; j < 7; ++j) {
      aw[j] = (j < len) ? exp2f((sv[j] - wm) * L2E) : 0.f;
      den += aw[j];
    }
    float inv = (den > 0.f) ? 1.f / den : 0.f;
    #pragma unroll
    for (int j = 0; j < 7; ++j) aw[j] *= inv;
    #pragma unroll
    for (int r = 0; r < 12; ++r) {
      int h = l + 64 * r;
      float acc = 0.f;
      #pragma unroll
      for (int j = 0; j < 7; ++j)
        if (j < len) acc += aw[j] * hidden[(size_t)(b * 512 + st + j) * 768 + h];
      pooled[span * 768 + h] = f2bf(acc);
    }
  } else if (bid < 144) {
    // k2a: wave w -> chunk (bid-128)*4 + w, lane = sequence
    const int b = l, c = (bid - 128) * 4 + w;
    float T0 = trans[0], T1 = trans[1], T2 = trans[2];
    float T3 = trans[3], T4 = trans[4], T5 = trans[5];
    float T6 = trans[6], T7 = trans[7], T8 = trans[8];
    const int L = lengths[b];
    const int s0 = 8 * c;
    int labp = labels_t[(c ? (s0 - 1) : 0) * 64 + b];

    float E0[8], E1[8], E2[8]; int LB[8];
    #pragma unroll
    for (int i = 0; i < 8; ++i) {
      E0[i] = em_t[((s0 + i) * 3 + 0) * 64 + b];
      E1[i] = em_t[((s0 + i) * 3 + 1) * 64 + b];
      E2[i] = em_t[((s0 + i) * 3 + 2) * 64 + b];
      LB[i] = labels_t[(s0 + i) * 64 + b];
    }
    float M[9];
    #pragma unroll
    for (int i = 0; i < 9; ++i) M[i] = (i == 0 || i == 4 || i == 8) ? 0.f : NEGB;
    float sc = 0.f;
    #pragma unroll
    for (int i = 0; i < 8; ++i) {
      int s = s0 + i;
      bool act = (s >= 1) && (s < L);
      float N[9];
      #pragma unroll
      for (int r = 0; r < 3; ++r) {
        float ma = M[3 * r], mb = M[3 * r + 1], mc = M[3 * r + 2];
        N[3 * r + 0] = lse3(ma + T0, mb + T3, mc + T6) + E0[i];
        N[3 * r + 1] = lse3(ma + T1, mb + T4, mc + T7) + E1[i];
        N[3 * r + 2] = lse3(ma + T2, mb + T5, mc + T8) + E2[i];
      }
      #pragma unroll
      for (int r = 0; r < 9; ++r) M[r] = act ? N[r] : M[r];
      int lab = LB[i];
      float ev = sel3(E0[i], E1[i], E2[i], lab);
      float trv = sel3(sel3(T0, T1, T2, lab),
                       sel3(T3, T4, T5, lab),
                       sel3(T6, T7, T8, lab), labp);
      sc += act ? (ev + trv) : 0.f;
      labp = lab;
    }
    #pragma unroll
    for (int i = 0; i < 9; ++i) matM[(c * 9 + i) * 64 + b] = M[i];
    psc[c * 64 + b] = sc;
  } else {
    // wt_type transpose: tile tb = bid-144 (96 tiles: 12 k x 8 n)
    __shared__ float tl[64][65];
    const int tb = bid - 144;
    const int k0 = (tb % 12) * 64;
    const int n0 = (tb / 12) * 64;
    const int n = t & 63;
    #pragma unroll
    for (int i = 0; i < 16; ++i) {
      int k = i * 4 + (t >> 6);
      tl[k][n] = (n0 + n < 500) ? Wtype[(size_t)(k0 + k) * 500 + n0 + n] : 0.f;
    }
    __syncthreads();
    const int k = t & 63;
    #pragma unroll
    for (int i = 0; i < 16; ++i) {
      int nn = i * 4 + (t >> 6);
      wt_type[(size_t)(n0 + nn) * 768 + k0 + k] = f2bf(tl[k][nn]);
    }
  }
}

// ---------------- K_tg3: type-GEMM partials (512 blocks) + last-block final ------------------
__global__ __launch_bounds__(256) void k_tg3(
    const unsigned short* __restrict__ pooled, const unsigned short* __restrict__ wt_type,
    const float* __restrict__ btype, const int* __restrict__ tlab,
    const int* __restrict__ tpos, const float* __restrict__ em_t,
    const int* __restrict__ labels_t, const int* __restrict__ lengths,
    const float* __restrict__ strans, const float* __restrict__ etrans,
    const float* __restrict__ matM, const float* __restrict__ psc,
    float* __restrict__ pq, float* __restrict__ vlbuf,
    unsigned* __restrict__ cnt, float* __restrict__ out) {
  __shared__ unsigned short Apool[8][776];     // 12416 B
  __shared__ uint4 Bt[6][512];                 // 49152 B
  __shared__ float logitsL[8][68];             // 2176 B
  __shared__ float red[16];
  __shared__ int last_flag;
  const int t = threadIdx.x, w = t >> 6, l = t & 63;
  const int b = blockIdx.x >> 3, oc = blockIdx.x & 7;
  const int c16 = l & 15, q = l >> 4;

  // stage A-tile (8 rows x 768 bf16) once
  #pragma unroll
  for (int u = 0; u < 3; ++u) {
    int i = u * 256 + t;
    int row = i / 96, c8 = i % 96;
    *(uint4*)(&Apool[row][c8 * 8]) =
        *(const uint4*)(pooled + (size_t)(b * 8 + row) * 768 + c8 * 8);
  }

  auto stageB = [&](int kt) {
    const int bi = kt % 6;
    #pragma unroll
    for (int u = 0; u < 2; ++u) {
      int i = u * 256 + t;
      int row = i >> 3;
      int ss = (i & 7) ^ (row & 7);
      gload_lds16(wt_type + (size_t)(oc * 64 + row) * 768 + kt * 64 + 8 * ss,
                  (void*)(Bt[bi] + i));
    }
  };

  stageB(0); stageB(1); stageB(2);
  f32x4 acc = (f32x4){0.f, 0.f, 0.f, 0.f};
  const bf16x8 zerov = (bf16x8)(__bf16)0.f;
  for (int kt = 0; kt < 12; ++kt) {
    if (kt < 9)        { stageB(kt + 3); asm volatile("s_waitcnt vmcnt(6)" ::: "memory"); }
    else if (kt == 9)  asm volatile("s_waitcnt vmcnt(4)" ::: "memory");
    else if (kt == 10) asm volatile("s_waitcnt vmcnt(2)" ::: "memory");
    else               asm volatile("s_waitcnt vmcnt(0)" ::: "memory");
    __builtin_amdgcn_s_barrier();
    __builtin_amdgcn_sched_barrier(0);

    const char* Bb = (const char*)Bt[kt % 6];
    const int brow = 16 * w + c16, r7 = brow & 7;
    #pragma unroll
    for (int ks = 0; ks < 2; ++ks) {
      bf16x8 a = (c16 < 8) ? *(const bf16x8*)(&Apool[c16][kt * 64 + ks * 32 + 8 * q]) : zerov;
      bf16x8 bb = *(const bf16x8*)(Bb + brow * 128 + (((ks * 4 + q) ^ r7) << 4));
      acc = __builtin_amdgcn_mfma_f32_16x16x32_bf16(a, bb, acc, 0, 0, 0);
    }
  }
  if (q < 2) {
    #pragma unroll
    for (int r = 0; r < 4; ++r) logitsL[4 * q + r][16 * w + c16] = acc[r];
  }
  __syncthreads();

  #pragma unroll
  for (int rr = 0; rr < 2; ++rr) {
    const int row = 2 * w + rr;
    int gc = 64 * oc + l;
    bool ok = gc < 500;
    float lv = ok ? logitsL[row][l] + btype[gc] : -1e30f;
    float m = lv;
    #pragma unroll
    for (int off = 1; off < 64; off <<= 1) m = fmaxf(m, __shfl_xor(m, off, 64));
    float se = ok ? exp2f((lv - m) * L2E) : 0.f;
    float ss = ok ? lv : 0.f;
    #pragma unroll
    for (int off = 1; off < 64; off <<= 1) {
      se += __shfl_xor(se, off, 64);
      ss += __shfl_xor(ss, off, 64);
    }
    if (l == 0) {
      int grow = b * 8 + row;
      float* dst = pq + ((size_t)grow * 8 + oc) * 4;
      dst[0] = m; dst[1] = se; dst[2] = ss;
      int lbl = tlab[grow];
      if ((lbl >> 6) == oc) vlbuf[grow] = logitsL[row][lbl & 63] + btype[lbl];
    }
  }

  // -------- last-block: focal combine + CRF chunk-scan + output --------
  __syncthreads();
  if (t == 0) {
    __threadfence();
    unsigned old = atomicAdd(cnt, 1u);
    last_flag = (old == 511u);
  }
  __syncthreads();
  if (!last_flag) return;
  __threadfence();

  float fsum = 0.f, vsum = 0.f;
  #pragma unroll
  for (int rr = 0; rr < 2; ++rr) {
    int row = t + 256 * rr;
    const float* p0 = pq + (size_t)row * 32;
    float gm = -1e30f;
    #pragma unroll
    for (int o = 0; o < 8; ++o) gm = fmaxf(gm, p0[4 * o]);
    float se = 0.f, ss = 0.f;
    #pragma unroll
    for (int o = 0; o < 8; ++o) {
      se += p0[4 * o + 1] * exp2f((p0[4 * o] - gm) * L2E);
      ss += p0[4 * o + 2];
    }
    float logZ = gm + log2f(se) * LN2;
    float lp = vlbuf[row] - logZ;
    float ce = -(0.9f * lp + 2e-4f * (ss - 500.f * logZ));
    float pt = 0.9f * exp2f(lp * L2E) + 2e-4f;
    float focal = ce * (1.f - pt) * (1.f - pt);
    bool valid = (tpos[row * 2] + tpos[row * 2 + 1]) > 0;
    fsum += valid ? focal : 0.f;
    vsum += valid ? 1.f : 0.f;
  }
  #pragma unroll
  for (int off = 1; off < 64; off <<= 1) {
    fsum += __shfl_xor(fsum, off, 64);
    vsum += __shfl_xor(vsum, off, 64);
  }
  if (l == 0) { red[w * 2] = fsum; red[w * 2 + 1] = vsum; }
  __syncthreads();
  if (t == 0) {
    red[8] = red[0] + red[2] + red[4] + red[6];
    red[9] = red[1] + red[3] + red[5] + red[7];
  }
  __syncthreads();

  if (t < 64) {
    const int b2_ = t;
    const int L = lengths[b2_];
    const float st0 = strans[0], st1 = strans[1], st2 = strans[2];
    const float et0 = etrans[0], et1 = etrans[1], et2 = etrans[2];
    float e00 = em_t[0 * 64 + b2_], e01 = em_t[1 * 64 + b2_], e02 = em_t[2 * 64 + b2_];
    int lab0 = labels_t[b2_];
    float a0 = st0 + e00, a1 = st1 + e01, a2 = st2 + e02;
    float score = sel3(st0, st1, st2, lab0) + sel3(e00, e01, e02, lab0);

    float cur[4][10];
    #pragma unroll
    for (int j = 0; j < 4; ++j) {
      #pragma unroll
      for (int i = 0; i < 9; ++i) cur[j][i] = matM[(j * 9 + i) * 64 + b2_];
      cur[j][9] = psc[j * 64 + b2_];
    }
    for (int r = 0; r < 16; ++r) {
      float nxt[4][10];
      if (r < 15) {
        #pragma unroll
        for (int j = 0; j < 4; ++j) {
          int c = (r + 1) * 4 + j;
          #pragma unroll
          for (int i = 0; i < 9; ++i) nxt[j][i] = matM[(c * 9 + i) * 64 + b2_];
          nxt[j][9] = psc[c * 64 + b2_];
        }
      }
      #pragma unroll
      for (int j = 0; j < 4; ++j) {
        float n0 = lse3(a0 + cur[j][0], a1 + cur[j][3], a2 + cur[j][6]);
        float n1 = lse3(a0 + cur[j][1], a1 + cur[j][4], a2 + cur[j][7]);
        float n2 = lse3(a0 + cur[j][2], a1 + cur[j][5], a2 + cur[j][8]);
        a0 = n0; a1 = n1; a2 = n2;
        score += cur[j][9];
      }
      if (r < 15) {
        #pragma unroll
        for (int j = 0; j < 4; ++j)
          #pragma unroll
          for (int i = 0; i < 10; ++i) cur[j][i] = nxt[j][i];
      }
    }
    int last = labels_t[(L - 1) * 64 + b2_];
    score += sel3(et0, et1, et2, last);
    float logZ = lse3(a0 + et0, a1 + et1, a2 + et2);
    float nll = logZ - score;
    #pragma unroll
    for (int off = 1; off < 64; off <<= 1) nll += __shfl_xor(nll, off, 64);
    if (b2_ == 0) {
      float pos = nll / 64.f;
      float type = red[8] / fmaxf(red[9], 1.f) * 10.f;
      out[0] = 0.6f * pos + 0.4f * type;
      out[1] = pos;
      out[2] = type;
    }
  }
}

extern "C" void kernel_launch(void* const* d_in, const int* in_sizes, int n_in,
                              void* d_out, int out_size, void* d_ws, size_t ws_size,
                              hipStream_t stream) {
  const float* hidden = (const float*)d_in[0];
  const int*   amask  = (const int*)d_in[1];
  const int*   plab   = (const int*)d_in[2];
  const int*   tlab   = (const int*)d_in[3];
  const int*   tpos   = (const int*)d_in[4];
  const float* biw    = (const float*)d_in[5];
  const float* Wpos   = (const float*)d_in[6];
  const float* bpos   = (const float*)d_in[7];
  const float* strans = (const float*)d_in[8];
  const float* etrans = (const float*)d_in[9];
  const float* trans  = (const float*)d_in[10];
  const float* W1     = (const float*)d_in[11];
  const float* b1     = (const float*)d_in[12];
  const float* W2     = (const float*)d_in[13];
  const float* b2     = (const float*)d_in[14];
  const float* Wtype  = (const float*)d_in[15];
  const float* btype  = (const float*)d_in[16];
  float* out = (float*)d_out;
  char* ws = (char*)d_ws;

  unsigned short* wt_all  = (unsigned short*)(ws + WT_ALL_OFF);
  unsigned short* wt_type = (unsigned short*)(ws + WT_TYPE_OFF);
  float* em_t    = (float*)(ws + EM_T_OFF);
  float* scores  = (float*)(ws + SCORES_OFF);
  int*   labelsT = (int*)(ws + LABELS_T_OFF);
  int*   lengths = (int*)(ws + LEN_OFF);
  unsigned short* pooled = (unsigned short*)(ws + POOLED_OFF);
  unsigned* cnt  = (unsigned*)(ws + CNT_OFF);
  float* matM    = (float*)(ws + MATM_OFF);
  float* psc     = (float*)(ws + PSC_OFF);
  float* pq      = (float*)(ws + PQ_OFF);
  float* vlbuf   = (float*)(ws + VL_OFF);

  ka_prep<<<14, 256, 0, stream>>>(W1, Wpos, amask, wt_all, lengths, cnt);
  k1_gemm<<<512, 256, 0, stream>>>(hidden, plab, bpos, b1, W2, b2, biw, wt_all,
                                   em_t, scores, labelsT);
  kpc2<<<240, 256, 0, stream>>>(hidden, scores, tpos, pooled, em_t, labelsT, lengths,
                                trans, Wtype, wt_type, matM, psc);
  k_tg3<<<512, 256, 0, stream>>>(pooled, wt_type, btype, tlab, tpos, em_t, labelsT,
                                 lengths, strans, etrans, matM, psc, pq, vlbuf, cnt, out);
}

// Round 13
// 85.781 us; speedup vs baseline: 1.1107x; 1.1107x over previous
//
#include <hip/hip_runtime.h>

#define L2E 1.44269504088896340736f
#define LN2 0.69314718055994530942f
#define NEGB -1e30f

typedef float f32x4 __attribute__((ext_vector_type(4)));
typedef __bf16 bf16x8 __attribute__((ext_vector_type(8)));

// workspace layout (bytes)
static constexpr size_t WT_ALL_OFF   = 0;        // 80*768 bf16
static constexpr size_t WT_TYPE_OFF  = 122880;   // 512*768 bf16 (rows 500..511 zero)
static constexpr size_t EM_T_OFF     = 909312;   // 512*3*64 f32 (em_t[s][j][b])
static constexpr size_t SCORES_OFF   = 1302528;  // 64*512 f32
static constexpr size_t LABELS_T_OFF = 1433600;  // 512*64 i32
static constexpr size_t LEN_OFF      = 1564672;  // 64 i32
static constexpr size_t POOLED_OFF   = 2351360;  // 512*768 bf16
static constexpr size_t MATM_OFF     = 3400192;  // 64*9*64 f32
static constexpr size_t PSC_OFF      = 3547648;  // 64*64 f32
static constexpr size_t PQ_OFF       = 3564032;  // 512 rows * 8 octs * 4 f32 = 65536
static constexpr size_t VL_OFF       = 3629568;  // 512 f32

__device__ __forceinline__ unsigned short f2bf(float f) {
  unsigned u = __builtin_bit_cast(unsigned, f);
  u += 0x7FFFu + ((u >> 16) & 1u);
  return (unsigned short)(u >> 16);
}
__device__ __forceinline__ float sel3(float a, float b, float c, int i) {
  return i == 0 ? a : (i == 1 ? b : c);
}
__device__ __forceinline__ float lse3(float x, float y, float z) {
  float m = fmaxf(fmaxf(x, y), z);
  float p = exp2f((x - m) * L2E) + exp2f((y - m) * L2E) + exp2f((z - m) * L2E);
  return m + log2f(p) * LN2;
}
__device__ __forceinline__ bf16x8 pack8(float4 lo, float4 hi) {
  union { unsigned u[4]; bf16x8 v; } r;
  asm("v_cvt_pk_bf16_f32 %0, %1, %2" : "=v"(r.u[0]) : "v"(lo.x), "v"(lo.y));
  asm("v_cvt_pk_bf16_f32 %0, %1, %2" : "=v"(r.u[1]) : "v"(lo.z), "v"(lo.w));
  asm("v_cvt_pk_bf16_f32 %0, %1, %2" : "=v"(r.u[2]) : "v"(hi.x), "v"(hi.y));
  asm("v_cvt_pk_bf16_f32 %0, %1, %2" : "=v"(r.u[3]) : "v"(hi.z), "v"(hi.w));
  return r.v;
}
__device__ __forceinline__ void gload_lds16(const void* g, void* l) {
  __builtin_amdgcn_global_load_lds(
      (const __attribute__((address_space(1))) unsigned*)g,
      (__attribute__((address_space(3))) unsigned*)l, 16, 0, 0);
}

// ---------------- K_A: coalesced weight transposes + lengths ---------------------------------
__global__ __launch_bounds__(256) void ka_prep(
    const float* __restrict__ W1, const float* __restrict__ Wpos,
    const float* __restrict__ Wtype, const int* __restrict__ amask,
    unsigned short* __restrict__ wt_all, unsigned short* __restrict__ wt_type,
    int* __restrict__ lengths) {
  const int bid = blockIdx.x, t = threadIdx.x;
  if (bid < 108) {
    __shared__ float tl[64][65];
    const bool is_type = bid < 96;
    const int kt = is_type ? (bid % 12) : (bid - 96);
    const int k0 = kt * 64;
    const int n0 = is_type ? (bid / 12) * 64 : 0;
    const int ld = is_type ? 500 : 64;
    const int nlim = is_type ? 500 : 64;
    const float* src = is_type ? Wtype : W1;
    unsigned short* dst = is_type ? wt_type : wt_all;
    const int n = t & 63;
    #pragma unroll
    for (int i = 0; i < 16; ++i) {
      int k = i * 4 + (t >> 6);
      tl[k][n] = (n0 + n < nlim) ? src[(size_t)(k0 + k) * ld + n0 + n] : 0.f;
    }
    __syncthreads();
    const int k = t & 63;
    #pragma unroll
    for (int i = 0; i < 16; ++i) {
      int nn = i * 4 + (t >> 6);
      dst[(size_t)(n0 + nn) * 768 + k0 + k] = f2bf(tl[k][nn]);
    }
  } else if (bid == 108) {
    for (int idx = t; idx < 16 * 768; idx += 256) {
      int n = 64 + idx / 768, k = idx % 768;
      float v = (n < 67) ? Wpos[k * 3 + (n - 64)] : 0.f;
      wt_all[(size_t)n * 768 + k] = f2bf(v);
    }
  } else {
    __shared__ int part[256];
    int bb = t >> 2, qq = t & 3;
    const int4* mp = (const int4*)(amask + bb * 512 + qq * 128);
    int s = 0;
    #pragma unroll 8
    for (int i = 0; i < 32; ++i) { int4 v = mp[i]; s += v.x + v.y + v.z + v.w; }
    part[t] = s;
    __syncthreads();
    if (qq == 0) lengths[bb] = part[t] + part[t + 1] + part[t + 2] + part[t + 3];
  }
}

// ---------------- K1: [32768x768]@[768x80] bf16 MFMA, 8 waves/block (16 waves/CU) ------------
// wave w: row-tile m=w&3 (16 rows), n-group g=w>>2 (g0: tiles 0-2, g1: tiles 3-4).
// 4-buf depth-2 DMA pipeline, 1 A-DMA + 1 B-DMA per thread per chunk, vmcnt(4/2/0).
__global__ __launch_bounds__(512) void k1_gemm(
    const float* __restrict__ hidden, const int* __restrict__ plab,
    const float* __restrict__ bpos, const float* __restrict__ b1,
    const float* __restrict__ W2, const float* __restrict__ b2,
    const float* __restrict__ biw, const unsigned short* __restrict__ wt_all,
    float* __restrict__ em_t, float* __restrict__ scores, int* __restrict__ labels_t) {
  __shared__ uint4 As[4][512];
  __shared__ uint4 Bs[4][512];
  __shared__ float sp[64][2];
  const int t = threadIdx.x, w = t >> 6, l = t & 63;
  const int row0 = blockIdx.x * 64;
  const int c16 = l & 15, q = l >> 4;
  const int m = w & 3, g = w >> 2;

  f32x4 acc[3];
  #pragma unroll
  for (int j = 0; j < 3; ++j) acc[j] = (f32x4){0.f, 0.f, 0.f, 0.f};

  auto stage = [&](int it) {
    const int bi = it & 3;
    const int k0 = it * 32;
    { int row = t >> 3, ss = (t & 7) ^ (row & 7);
      gload_lds16(hidden + (size_t)(row0 + row) * 768 + k0 + 4 * ss, (void*)(As[bi] + t)); }
    { int row = t >> 2, ss = (t & 3) ^ ((row >> 1) & 3);
      gload_lds16(wt_all + (size_t)row * 768 + k0 + 8 * ss, (void*)(Bs[bi] + t)); }
  };

  stage(0); stage(1);
  for (int it = 0; it < 24; ++it) {
    if (it < 22) stage(it + 2);
    if (it < 22)       asm volatile("s_waitcnt vmcnt(4)" ::: "memory");
    else if (it == 22) asm volatile("s_waitcnt vmcnt(2)" ::: "memory");
    else               asm volatile("s_waitcnt vmcnt(0)" ::: "memory");
    __builtin_amdgcn_s_barrier();
    __builtin_amdgcn_sched_barrier(0);

    const int bi = it & 3;
    const char* Ab = (const char*)As[bi];
    const char* Bb = (const char*)Bs[bi];
    const int arow = 16 * m + c16, r7 = arow & 7;
    float4 alo = *(const float4*)(Ab + arow * 128 + (((2 * q + 0) ^ r7) << 4));
    float4 ahi = *(const float4*)(Ab + arow * 128 + (((2 * q + 1) ^ r7) << 4));
    bf16x8 a = pack8(alo, ahi);
    if (g == 0) {
      #pragma unroll
      for (int j = 0; j < 3; ++j) {
        const int brow = 16 * j + c16;
        bf16x8 b = *(const bf16x8*)(Bb + brow * 64 + ((q ^ ((brow >> 1) & 3)) << 4));
        acc[j] = __builtin_amdgcn_mfma_f32_16x16x32_bf16(a, b, acc[j], 0, 0, 0);
      }
    } else {
      #pragma unroll
      for (int j = 0; j < 2; ++j) {
        const int brow = 16 * (3 + j) + c16;
        bf16x8 b = *(const bf16x8*)(Bb + brow * 64 + ((q ^ ((brow >> 1) & 3)) << 4));
        acc[j] = __builtin_amdgcn_mfma_f32_16x16x32_bf16(a, b, acc[j], 0, 0, 0);
      }
    }
  }

  // epilogue: per-wave score partials over cols<64, assembled via sp[64][2]
  #pragma unroll
  for (int r = 0; r < 4; ++r) {
    float s = 0.f;
    if (g == 0) {
      #pragma unroll
      for (int j = 0; j < 3; ++j) {
        int c = 16 * j + c16;
        float x = acc[j][r] + b1[c];
        float th = 1.f - 2.f / (1.f + exp2f(x * (2.f * L2E)));
        s += th * W2[c];
      }
    } else {
      int c = 48 + c16;                       // tile 3 only (tile 4 = emissions, cols>=64)
      float x = acc[0][r] + b1[c];
      float th = 1.f - 2.f / (1.f + exp2f(x * (2.f * L2E)));
      s = th * W2[c];
    }
    #pragma unroll
    for (int off = 1; off < 16; off <<= 1) s += __shfl_xor(s, off, 64);
    if (c16 == 0) sp[16 * m + 4 * q + r][g] = s;
  }
  __syncthreads();

  if (g == 0) {
    const float bias2 = b2[0];
    #pragma unroll
    for (int r = 0; r < 4; ++r) {
      int row = 16 * m + 4 * q + r;
      if (c16 == 0) scores[row0 + row] = sp[row][0] + sp[row][1] + bias2;
    }
  } else if (c16 < 3) {
    const float bi = biw[0];
    #pragma unroll
    for (int r = 0; r < 4; ++r) {
      int row = row0 + 16 * m + 4 * q + r;
      int bb = row >> 9, ss = row & 511;
      int lab = plab[row];
      float wgt = (lab > 0) ? 1.f + bi : 1.f;
      float ev = (acc[1][r] + bpos[c16]) * wgt;   // tile 4, cols 64..66
      em_t[(ss * 3 + c16) * 64 + bb] = ev;
      if (c16 == 0) labels_t[ss * 64 + bb] = lab;
    }
  }
}

// ---------------- KPC: {bid<512: span pooling | bid>=512: CRF chunk matrices} ----------------
__global__ __launch_bounds__(64) void kpc(
    const float* __restrict__ hidden, const float* __restrict__ scores,
    const int* __restrict__ tpos, unsigned short* __restrict__ pooled,
    const float* __restrict__ em_t, const int* __restrict__ labels_t,
    const int* __restrict__ lengths, const float* __restrict__ trans,
    float* __restrict__ matM, float* __restrict__ psc) {
  const int bid = blockIdx.x, l = threadIdx.x;
  if (bid < 512) {
    const int span = bid;
    const int b = span >> 3;
    const int st = tpos[span * 2], en = tpos[span * 2 + 1];
    int len = (st + en > 0) ? (en - st) : 0;
    float sv[7], aw[7];
    float wm = -1e30f;
    #pragma unroll
    for (int j = 0; j < 7; ++j) {
      sv[j] = (j < len) ? scores[b * 512 + st + j] : -1e30f;
      wm = fmaxf(wm, sv[j]);
    }
    float den = 0.f;
    #pragma unroll
    for (int j = 0; j < 7; ++j) {
      aw[j] = (j < len) ? exp2f((sv[j] - wm) * L2E) : 0.f;
      den += aw[j];
    }
    float inv = (den > 0.f) ? 1.f / den : 0.f;
    #pragma unroll
    for (int j = 0; j < 7; ++j) aw[j] *= inv;
    #pragma unroll
    for (int r = 0; r < 12; ++r) {
      int h = l + 64 * r;
      float acc = 0.f;
      #pragma unroll
      for (int j = 0; j < 7; ++j)
        if (j < len) acc += aw[j] * hidden[(size_t)(b * 512 + st + j) * 768 + h];
      pooled[span * 768 + h] = f2bf(acc);
    }
  } else {
    const int b = l, c = bid - 512;
    float T0 = trans[0], T1 = trans[1], T2 = trans[2];
    float T3 = trans[3], T4 = trans[4], T5 = trans[5];
    float T6 = trans[6], T7 = trans[7], T8 = trans[8];
    const int L = lengths[b];
    const int s0 = 8 * c;
    int labp = labels_t[(c ? (s0 - 1) : 0) * 64 + b];

    float E0[8], E1[8], E2[8]; int LB[8];
    #pragma unroll
    for (int i = 0; i < 8; ++i) {
      E0[i] = em_t[((s0 + i) * 3 + 0) * 64 + b];
      E1[i] = em_t[((s0 + i) * 3 + 1) * 64 + b];
      E2[i] = em_t[((s0 + i) * 3 + 2) * 64 + b];
      LB[i] = labels_t[(s0 + i) * 64 + b];
    }
    float M[9];
    #pragma unroll
    for (int i = 0; i < 9; ++i) M[i] = (i == 0 || i == 4 || i == 8) ? 0.f : NEGB;
    float sc = 0.f;
    #pragma unroll
    for (int i = 0; i < 8; ++i) {
      int s = s0 + i;
      bool act = (s >= 1) && (s < L);
      float N[9];
      #pragma unroll
      for (int r = 0; r < 3; ++r) {
        float ma = M[3 * r], mb = M[3 * r + 1], mc = M[3 * r + 2];
        N[3 * r + 0] = lse3(ma + T0, mb + T3, mc + T6) + E0[i];
        N[3 * r + 1] = lse3(ma + T1, mb + T4, mc + T7) + E1[i];
        N[3 * r + 2] = lse3(ma + T2, mb + T5, mc + T8) + E2[i];
      }
      #pragma unroll
      for (int r = 0; r < 9; ++r) M[r] = act ? N[r] : M[r];
      int lab = LB[i];
      float ev = sel3(E0[i], E1[i], E2[i], lab);
      float trv = sel3(sel3(T0, T1, T2, lab),
                       sel3(T3, T4, T5, lab),
                       sel3(T6, T7, T8, lab), labp);
      sc += act ? (ev + trv) : 0.f;
      labp = lab;
    }
    #pragma unroll
    for (int i = 0; i < 9; ++i) matM[(c * 9 + i) * 64 + b] = M[i];
    psc[c * 64 + b] = sc;
  }
}

// ---------------- K_tg2: type-GEMM partials, 512 blocks (b x oct), DMA 6-buf depth-3 ---------
__global__ __launch_bounds__(256) void k_tg2(
    const unsigned short* __restrict__ pooled, const unsigned short* __restrict__ wt_type,
    const float* __restrict__ btype, const int* __restrict__ tlab,
    float* __restrict__ pq, float* __restrict__ vlbuf) {
  __shared__ unsigned short Apool[8][776];
  __shared__ uint4 Bt[6][512];
  __shared__ float logitsL[8][68];
  const int t = threadIdx.x, w = t >> 6, l = t & 63;
  const int b = blockIdx.x >> 3, oc = blockIdx.x & 7;
  const int c16 = l & 15, q = l >> 4;

  #pragma unroll
  for (int u = 0; u < 3; ++u) {
    int i = u * 256 + t;
    int row = i / 96, c8 = i % 96;
    *(uint4*)(&Apool[row][c8 * 8]) =
        *(const uint4*)(pooled + (size_t)(b * 8 + row) * 768 + c8 * 8);
  }

  auto stageB = [&](int kt) {
    const int bi = kt % 6;
    #pragma unroll
    for (int u = 0; u < 2; ++u) {
      int i = u * 256 + t;
      int row = i >> 3;
      int ss = (i & 7) ^ (row & 7);
      gload_lds16(wt_type + (size_t)(oc * 64 + row) * 768 + kt * 64 + 8 * ss,
                  (void*)(Bt[bi] + i));
    }
  };

  stageB(0); stageB(1); stageB(2);
  f32x4 acc = (f32x4){0.f, 0.f, 0.f, 0.f};
  const bf16x8 zerov = (bf16x8)(__bf16)0.f;
  for (int kt = 0; kt < 12; ++kt) {
    if (kt < 9)        { stageB(kt + 3); asm volatile("s_waitcnt vmcnt(6)" ::: "memory"); }
    else if (kt == 9)  asm volatile("s_waitcnt vmcnt(4)" ::: "memory");
    else if (kt == 10) asm volatile("s_waitcnt vmcnt(2)" ::: "memory");
    else               asm volatile("s_waitcnt vmcnt(0)" ::: "memory");
    __builtin_amdgcn_s_barrier();
    __builtin_amdgcn_sched_barrier(0);

    const char* Bb = (const char*)Bt[kt % 6];
    const int brow = 16 * w + c16, r7 = brow & 7;
    #pragma unroll
    for (int ks = 0; ks < 2; ++ks) {
      bf16x8 a = (c16 < 8) ? *(const bf16x8*)(&Apool[c16][kt * 64 + ks * 32 + 8 * q]) : zerov;
      bf16x8 bb = *(const bf16x8*)(Bb + brow * 128 + (((ks * 4 + q) ^ r7) << 4));
      acc = __builtin_amdgcn_mfma_f32_16x16x32_bf16(a, bb, acc, 0, 0, 0);
    }
  }
  if (q < 2) {
    #pragma unroll
    for (int r = 0; r < 4; ++r) logitsL[4 * q + r][16 * w + c16] = acc[r];
  }
  __syncthreads();

  #pragma unroll
  for (int rr = 0; rr < 2; ++rr) {
    const int row = 2 * w + rr;
    int gc = 64 * oc + l;
    bool ok = gc < 500;
    float lv = ok ? logitsL[row][l] + btype[gc] : -1e30f;
    float m = lv;
    #pragma unroll
    for (int off = 1; off < 64; off <<= 1) m = fmaxf(m, __shfl_xor(m, off, 64));
    float se = ok ? exp2f((lv - m) * L2E) : 0.f;
    float ss = ok ? lv : 0.f;
    #pragma unroll
    for (int off = 1; off < 64; off <<= 1) {
      se += __shfl_xor(se, off, 64);
      ss += __shfl_xor(ss, off, 64);
    }
    if (l == 0) {
      int grow = b * 8 + row;
      float* dst = pq + ((size_t)grow * 8 + oc) * 4;
      dst[0] = m; dst[1] = se; dst[2] = ss;
      int lbl = tlab[grow];
      if ((lbl >> 6) == oc) vlbuf[grow] = logitsL[row][lbl & 63] + btype[lbl];
    }
  }
}

// ---------------- K_final: focal oct-combine + CRF chunk-scan + output -----------------------
__global__ __launch_bounds__(256) void k_final(
    const float* __restrict__ pq, const float* __restrict__ vlbuf,
    const int* __restrict__ tpos, const float* __restrict__ em_t,
    const int* __restrict__ labels_t, const int* __restrict__ lengths,
    const float* __restrict__ strans, const float* __restrict__ etrans,
    const float* __restrict__ matM, const float* __restrict__ psc,
    float* __restrict__ out) {
  __shared__ float red[16];
  const int t = threadIdx.x, w = t >> 6, l = t & 63;

  float fsum = 0.f, vsum = 0.f;
  #pragma unroll
  for (int rr = 0; rr < 2; ++rr) {
    int row = t + 256 * rr;
    const float* p0 = pq + (size_t)row * 32;
    float gm = -1e30f;
    #pragma unroll
    for (int o = 0; o < 8; ++o) gm = fmaxf(gm, p0[4 * o]);
    float se = 0.f, ss = 0.f;
    #pragma unroll
    for (int o = 0; o < 8; ++o) {
      se += p0[4 * o + 1] * exp2f((p0[4 * o] - gm) * L2E);
      ss += p0[4 * o + 2];
    }
    float logZ = gm + log2f(se) * LN2;
    float lp = vlbuf[row] - logZ;
    float ce = -(0.9f * lp + 2e-4f * (ss - 500.f * logZ));
    float pt = 0.9f * exp2f(lp * L2E) + 2e-4f;
    float focal = ce * (1.f - pt) * (1.f - pt);
    bool valid = (tpos[row * 2] + tpos[row * 2 + 1]) > 0;
    fsum += valid ? focal : 0.f;
    vsum += valid ? 1.f : 0.f;
  }
  #pragma unroll
  for (int off = 1; off < 64; off <<= 1) {
    fsum += __shfl_xor(fsum, off, 64);
    vsum += __shfl_xor(vsum, off, 64);
  }
  if (l == 0) { red[w * 2] = fsum; red[w * 2 + 1] = vsum; }
  __syncthreads();
  if (t == 0) {
    red[8] = red[0] + red[2] + red[4] + red[6];
    red[9] = red[1] + red[3] + red[5] + red[7];
  }
  __syncthreads();

  if (t < 64) {
    const int b = t;
    const int L = lengths[b];
    const float st0 = strans[0], st1 = strans[1], st2 = strans[2];
    const float et0 = etrans[0], et1 = etrans[1], et2 = etrans[2];
    float e00 = em_t[0 * 64 + b], e01 = em_t[1 * 64 + b], e02 = em_t[2 * 64 + b];
    int lab0 = labels_t[b];
    float a0 = st0 + e00, a1 = st1 + e01, a2 = st2 + e02;
    float score = sel3(st0, st1, st2, lab0) + sel3(e00, e01, e02, lab0);

    float cur[4][10];
    #pragma unroll
    for (int j = 0; j < 4; ++j) {
      #pragma unroll
      for (int i = 0; i < 9; ++i) cur[j][i] = matM[(j * 9 + i) * 64 + b];
      cur[j][9] = psc[j * 64 + b];
    }
    for (int r = 0; r < 16; ++r) {
      float nxt[4][10];
      if (r < 15) {
        #pragma unroll
        for (int j = 0; j < 4; ++j) {
          int c = (r + 1) * 4 + j;
          #pragma unroll
          for (int i = 0; i < 9; ++i) nxt[j][i] = matM[(c * 9 + i) * 64 + b];
          nxt[j][9] = psc[c * 64 + b];
        }
      }
      #pragma unroll
      for (int j = 0; j < 4; ++j) {
        float n0 = lse3(a0 + cur[j][0], a1 + cur[j][3], a2 + cur[j][6]);
        float n1 = lse3(a0 + cur[j][1], a1 + cur[j][4], a2 + cur[j][7]);
        float n2 = lse3(a0 + cur[j][2], a1 + cur[j][5], a2 + cur[j][8]);
        a0 = n0; a1 = n1; a2 = n2;
        score += cur[j][9];
      }
      if (r < 15) {
        #pragma unroll
        for (int j = 0; j < 4; ++j)
          #pragma unroll
          for (int i = 0; i < 10; ++i) cur[j][i] = nxt[j][i];
      }
    }
    int last = labels_t[(L - 1) * 64 + b];
    score += sel3(et0, et1, et2, last);
    float logZ = lse3(a0 + et0, a1 + et1, a2 + et2);
    float nll = logZ - score;
    #pragma unroll
    for (int off = 1; off < 64; off <<= 1) nll += __shfl_xor(nll, off, 64);
    if (b == 0) {
      float pos = nll / 64.f;
      float type = red[8] / fmaxf(red[9], 1.f) * 10.f;
      out[0] = 0.6f * pos + 0.4f * type;
      out[1] = pos;
      out[2] = type;
    }
  }
}

extern "C" void kernel_launch(void* const* d_in, const int* in_sizes, int n_in,
                              void* d_out, int out_size, void* d_ws, size_t ws_size,
                              hipStream_t stream) {
  const float* hidden = (const float*)d_in[0];
  const int*   amask  = (const int*)d_in[1];
  const int*   plab   = (const int*)d_in[2];
  const int*   tlab   = (const int*)d_in[3];
  const int*   tpos   = (const int*)d_in[4];
  const float* biw    = (const float*)d_in[5];
  const float* Wpos   = (const float*)d_in[6];
  const float* bpos   = (const float*)d_in[7];
  const float* strans = (const float*)d_in[8];
  const float* etrans = (const float*)d_in[9];
  const float* trans  = (const float*)d_in[10];
  const float* W1     = (const float*)d_in[11];
  const float* b1     = (const float*)d_in[12];
  const float* W2     = (const float*)d_in[13];
  const float* b2     = (const float*)d_in[14];
  const float* Wtype  = (const float*)d_in[15];
  const float* btype  = (const float*)d_in[16];
  float* out = (float*)d_out;
  char* ws = (char*)d_ws;

  unsigned short* wt_all  = (unsigned short*)(ws + WT_ALL_OFF);
  unsigned short* wt_type = (unsigned short*)(ws + WT_TYPE_OFF);
  float* em_t    = (float*)(ws + EM_T_OFF);
  float* scores  = (float*)(ws + SCORES_OFF);
  int*   labelsT = (int*)(ws + LABELS_T_OFF);
  int*   lengths = (int*)(ws + LEN_OFF);
  unsigned short* pooled = (unsigned short*)(ws + POOLED_OFF);
  float* matM    = (float*)(ws + MATM_OFF);
  float* psc     = (float*)(ws + PSC_OFF);
  float* pq      = (float*)(ws + PQ_OFF);
  float* vlbuf   = (float*)(ws + VL_OFF);

  ka_prep<<<110, 256, 0, stream>>>(W1, Wpos, Wtype, amask, wt_all, wt_type, lengths);
  k1_gemm<<<512, 512, 0, stream>>>(hidden, plab, bpos, b1, W2, b2, biw, wt_all,
                                   em_t, scores, labelsT);
  kpc<<<576, 64, 0, stream>>>(hidden, scores, tpos, pooled, em_t, labelsT, lengths,
                              trans, matM, psc);
  k_tg2<<<512, 256, 0, stream>>>(pooled, wt_type, btype, tlab, pq, vlbuf);
  k_final<<<1, 256, 0, stream>>>(pq, vlbuf, tpos, em_t, labelsT, lengths,
                                 strans, etrans, matM, psc, out);
}